// Round 3
// baseline (320.049 us; speedup 1.0000x reference)
//
#include <hip/hip_runtime.h>
#include <math.h>

#define B_   256
#define S_   4
#define W1_  64
#define W2_  128
#define D_   300
#define HID_ 4
#define KT   60     // K tile: 300 = 5 * 60
#define NKT  5
#define NG   15     // float4 granules per K tile
#define PADK 64     // padded LDS row stride (floats)

// Per-(b,s) similarity + threshold count.
// Block = one (b,s) slot, 256 threads = 4 waves.
// Wave w owns K-share w (granule range within each K-tile)  -> ALL waves compute.
// Thread tile = 4x8 outputs (best LDS-read:FMA ratio, conflict-free pattern).
// Partial sums reduced across the 4 shares via LDS epilogue, then thresholded.
__global__ __launch_bounds__(256) void sim_count_kernel(
    const float* __restrict__ t1, const float* __restrict__ t2,
    const int* __restrict__ m1, const int* __restrict__ m2,
    const float* __restrict__ thr_p, float* __restrict__ norm_out)
{
    __shared__ float As[W1_ * PADK];   // 16 KB
    __shared__ float Bs[W2_ * PADK];   // 32 KB; reused as Ps[32][4][64] in epilogue
    __shared__ int widx[W1_];
    __shared__ int vidx[W2_];
    __shared__ int cntA, cntB, cntOv;

    const int bs  = blockIdx.x;        // b*S + s
    const int tid = threadIdx.x;
    const float thr = *thr_p;

    if (tid == 0) { cntA = 0; cntB = 0; cntOv = 0; }
    __syncthreads();

    // --- compaction: active-row index lists (order irrelevant, we only count) ---
    if (tid < W1_) {
        if (m1[bs * W1_ + tid] != 0) { int p = atomicAdd(&cntA, 1); widx[p] = tid; }
    } else if (tid < W1_ + W2_) {
        int v = tid - W1_;
        if (m2[bs * W2_ + v] != 0) { int p = atomicAdd(&cntB, 1); vidx[p] = v; }
    }
    __syncthreads();

    const int nA = cntA, nB = cntB;
    const int Ra = (nA + 3) >> 2;      // 4-row tiles
    const int Cb = (nB + 7) >> 3;      // 8-col tiles
    const int Ta = Ra * Cb;            // active output tiles (<= 256)
    const int nChunks = (Ta + 63) >> 6;

    const int sh = tid >> 6;           // K-share, wave-uniform
    const int tl = tid & 63;           // chunk-local tile id
    const int gs = (NG * sh) >> 2;     // granule range [gs, ge) per share: 3/4/4/4
    const int ge = (NG * (sh + 1)) >> 2;

    float* Ps = Bs;                    // epilogue partial buffer (union with Bs)

    const float* t1b = t1 + (size_t)bs * W1_ * D_;
    const float* t2b = t2 + (size_t)bs * W2_ * D_;

    for (int chunk = 0; chunk < nChunks; ++chunk) {
        const int T = chunk * 64 + tl;
        const bool active = (T < Ta);
        int tr = 0, tc = 0;
        if (active) { tr = T / Cb; tc = T - tr * Cb; }
        const int swa = tr & 7;        // = ((4*tr+i)>>2)&7, i<4
        const int swb = tc & 7;        // = ((8*tc+j)>>3)&7, j<8

        // acc: compile-time indices only (rule #20 — round-1 scratch lesson)
        float acc[4][8];
        #pragma unroll
        for (int i = 0; i < 4; ++i)
            #pragma unroll
            for (int j = 0; j < 8; ++j) acc[i][j] = 0.f;

        for (int kt = 0; kt < NKT; ++kt) {
            const int k0 = kt * KT;
            // --- stage active rows (coalesced float4, XOR-swizzled granule) ---
            for (int idx = tid; idx < nA * NG; idx += 256) {
                int a = idx / NG;
                int f = idx - a * NG;
                const float4 val = *reinterpret_cast<const float4*>(
                    t1b + (size_t)widx[a] * D_ + k0 + 4 * f);
                *reinterpret_cast<float4*>(
                    &As[a * PADK + 4 * (f ^ ((a >> 2) & 7))]) = val;
            }
            for (int idx = tid; idx < nB * NG; idx += 256) {
                int v = idx / NG;
                int f = idx - v * NG;
                const float4 val = *reinterpret_cast<const float4*>(
                    t2b + (size_t)vidx[v] * D_ + k0 + 4 * f);
                *reinterpret_cast<float4*>(
                    &Bs[v * PADK + 4 * (f ^ ((v >> 3) & 7))]) = val;
            }
            __syncthreads();

            if (active) {
                for (int g = gs; g < ge; ++g) {
                    float4 av[4];
                    float4 bv[8];
                    #pragma unroll
                    for (int i = 0; i < 4; ++i)
                        av[i] = *reinterpret_cast<const float4*>(
                            &As[(4 * tr + i) * PADK + 4 * (g ^ swa)]);
                    #pragma unroll
                    for (int j = 0; j < 8; ++j)
                        bv[j] = *reinterpret_cast<const float4*>(
                            &Bs[(8 * tc + j) * PADK + 4 * (g ^ swb)]);
                    #pragma unroll
                    for (int i = 0; i < 4; ++i)
                        #pragma unroll
                        for (int j = 0; j < 8; ++j) {
                            acc[i][j] = fmaf(av[i].x, bv[j].x, acc[i][j]);
                            acc[i][j] = fmaf(av[i].y, bv[j].y, acc[i][j]);
                            acc[i][j] = fmaf(av[i].z, bv[j].z, acc[i][j]);
                            acc[i][j] = fmaf(av[i].w, bv[j].w, acc[i][j]);
                        }
                }
            }
            __syncthreads();   // before next K-tile overwrites LDS
        }

        // --- cross-share reduction via LDS (Bs region is free now) ---
        // Layout Ps[o][share][tile]: stride-1 in tile -> conflict-free.
        #pragma unroll
        for (int i = 0; i < 4; ++i)
            #pragma unroll
            for (int j = 0; j < 8; ++j)
                Ps[(i * 8 + j) * 256 + sh * 64 + tl] = acc[i][j];
        __syncthreads();

        // Each thread: tile tl, output rows i == sh, cols j = 0..7.
        int lc = 0;
        if (active) {
            #pragma unroll
            for (int j = 0; j < 8; ++j) {
                const int o = sh * 8 + j;       // i = sh
                float sum = Ps[o * 256 + 0 * 64 + tl] + Ps[o * 256 + 1 * 64 + tl]
                          + Ps[o * 256 + 2 * 64 + tl] + Ps[o * 256 + 3 * 64 + tl];
                const bool valid = (4 * tr + sh < nA) && (8 * tc + j < nB);
                lc += (valid && (sum >= thr)) ? 1 : 0;
            }
        }
        #pragma unroll
        for (int o = 32; o > 0; o >>= 1) lc += __shfl_down(lc, o);
        if ((tid & 63) == 0 && lc != 0) atomicAdd(&cntOv, lc);
        __syncthreads();   // Ps/Bs reuse + cntOv visibility before next chunk
    }

    if (tid == 0) {
        float divisor = (nA == 0) ? 1e-7f : (float)nA;
        norm_out[bs] = (float)cntOv / divisor;
    }
}

// Tiny MLP head: h = tanh(norm @ Wh), out = sigmoid(h @ Ws)
__global__ __launch_bounds__(256) void head_kernel(
    const float* __restrict__ norm,
    const float* __restrict__ Wh,   // (S, HID) row-major
    const float* __restrict__ Ws,   // (HID, 1)
    float* __restrict__ out)
{
    int b = blockIdx.x * blockDim.x + threadIdx.x;
    if (b >= B_) return;
    float4 n = *reinterpret_cast<const float4*>(norm + b * 4);
    float score = 0.f;
    #pragma unroll
    for (int j = 0; j < HID_; ++j) {
        float h = n.x * Wh[0 * HID_ + j] + n.y * Wh[1 * HID_ + j]
                + n.z * Wh[2 * HID_ + j] + n.w * Wh[3 * HID_ + j];
        h = tanhf(h);
        score += h * Ws[j];
    }
    out[b] = 1.f / (1.f + expf(-score));
}

extern "C" void kernel_launch(void* const* d_in, const int* in_sizes, int n_in,
                              void* d_out, int out_size, void* d_ws, size_t ws_size,
                              hipStream_t stream)
{
    const float* t1  = (const float*)d_in[0];
    const float* t2  = (const float*)d_in[1];
    const int*   m1  = (const int*)d_in[2];
    const int*   m2  = (const int*)d_in[3];
    const float* thr = (const float*)d_in[4];
    const float* Wh  = (const float*)d_in[5];
    const float* Ws  = (const float*)d_in[6];
    float* out  = (float*)d_out;
    float* norm = (float*)d_ws;   // 1024 floats

    sim_count_kernel<<<B_ * S_, 256, 0, stream>>>(t1, t2, m1, m2, thr, norm);
    head_kernel<<<1, 256, 0, stream>>>(norm, Wh, Ws, out);
}

// Round 4
// 297.753 us; speedup vs baseline: 1.0749x; 1.0749x over previous
//
#include <hip/hip_runtime.h>
#include <math.h>

#define B_    256
#define S_    4
#define W1_   64
#define W2_   128
#define D_    300
#define HID_  4
#define KTILE 64        // k-elements per staged tile
#define NT    5         // 5 * 64 = 320 >= 300 (zero-padded tail)

typedef short          s16x8 __attribute__((ext_vector_type(8)));
typedef float          fx4   __attribute__((ext_vector_type(4)));
typedef unsigned short us4   __attribute__((ext_vector_type(4)));

// LDS byte map (row stride 128 B = 64 bf16)
#define AHI_OFF 0
#define ALO_OFF 8192
#define BHI_OFF 16384
#define BLO_OFF 32768
#define LDS_BYTES 49152

// Split f32 into hi+lo bf16 (RNE via bit trick). a ~= hi + lo with ~2^-17 rel residual.
__device__ __forceinline__ void split_bf16(float x, unsigned short& h, unsigned short& l) {
    union { float f; unsigned u; } c; c.f = x;
    unsigned uh = c.u + 0x7FFFu + ((c.u >> 16) & 1u);
    h = (unsigned short)(uh >> 16);
    union { unsigned u; float f; } hb; hb.u = ((unsigned)h) << 16;
    float r = x - hb.f;
    union { float f; unsigned u; } cr; cr.f = r;
    unsigned ul = cr.u + 0x7FFFu + ((cr.u >> 16) & 1u);
    l = (unsigned short)(ul >> 16);
}

// Dense MFMA similarity-count. Block = one (b,s) slot, 256 thr = 4 waves.
// S = Ah*Bh + Ah*Bl + Al*Bh (hi/lo bf16 split of f32), masks applied in epilogue.
__global__ __launch_bounds__(256, 3) void sim_count_mfma(
    const float* __restrict__ t1, const float* __restrict__ t2,
    const int* __restrict__ m1, const int* __restrict__ m2,
    const float* __restrict__ thr_p, float* __restrict__ norm_out)
{
    __shared__ unsigned char lds[LDS_BYTES];
    __shared__ int m1s[W1_];
    __shared__ int m2s[W2_];
    __shared__ int sh_nA, sh_cnt;

    const int bs  = blockIdx.x;
    const int tid = threadIdx.x;
    const float thr = *thr_p;

    const float* t1b = t1 + (size_t)bs * W1_ * D_;
    const float* t2b = t2 + (size_t)bs * W2_ * D_;

    if (tid == 0) sh_cnt = 0;
    if (tid < W1_) {                       // wave 0 exactly
        int m = m1[bs * W1_ + tid];
        m1s[tid] = m;
        unsigned long long bal = __ballot(m != 0);
        if (tid == 0) sh_nA = __popcll(bal);
    } else if (tid < W1_ + W2_) {
        m2s[tid - W1_] = m2[bs * W2_ + (tid - W1_)];
    }

    // --- staging: 3072 float4 granules/tile (A 64x16, B 128x16) = 12/thread ---
    fx4 stg[12];   // compile-time indexed only (rule #20)

    auto stage_issue = [&](int t) {
        #pragma unroll
        for (int p = 0; p < 12; ++p) {
            const int idx = tid + (p << 8);
            const bool isA = (idx < 1024);
            const int sub = isA ? idx : idx - 1024;
            const int row = sub >> 4;
            const int g   = sub & 15;
            const float* src = (isA ? t1b : t2b) + row * D_ + t * KTILE + 4 * g;
            fx4 v; v[0] = 0.f; v[1] = 0.f; v[2] = 0.f; v[3] = 0.f;
            if ((t < 4) | (g <= 10)) v = *(const fx4*)src;   // k>=300 -> zeros
            stg[p] = v;
        }
    };
    auto cvt_write = [&]() {
        #pragma unroll
        for (int p = 0; p < 12; ++p) {
            const int idx = tid + (p << 8);
            const bool isA = (idx < 1024);
            const int sub = isA ? idx : idx - 1024;
            const int row = sub >> 4;
            const int g   = sub & 15;
            us4 hv, lv;
            #pragma unroll
            for (int e = 0; e < 4; ++e) {
                unsigned short h, l;
                split_bf16(stg[p][e], h, l);
                hv[e] = h; lv[e] = l;
            }
            // T2 XOR swizzle, same key on write and read (rule #21)
            const int off = (g * 8) ^ ((row & 7) << 4);
            unsigned char* ph = lds + (isA ? AHI_OFF : BHI_OFF) + row * 128 + off;
            unsigned char* pl = lds + (isA ? ALO_OFF : BLO_OFF) + row * 128 + off;
            *(us4*)ph = hv;
            *(us4*)pl = lv;
        }
    };

    // --- fragment geometry: wave w -> A rows 16w..16w+15, all 128 cols ---
    const int l  = tid & 63;
    const int w  = tid >> 6;
    const int lr = l & 15;        // frag row (A) / col (B)
    const int lg = l >> 4;        // k-group: k = lg*8 + e
    const int arow  = (w << 4) + lr;
    const int abase = arow * 128;
    const int asw   = (arow & 7) << 4;

    fx4 acc[8];
    {
        fx4 z; z[0] = 0.f; z[1] = 0.f; z[2] = 0.f; z[3] = 0.f;
        #pragma unroll
        for (int ct = 0; ct < 8; ++ct) acc[ct] = z;
    }

    stage_issue(0);
    cvt_write();
    __syncthreads();

    for (int t = 0; t < NT; ++t) {
        if (t + 1 < NT) stage_issue(t + 1);   // T14: issue early, write late
        #pragma unroll
        for (int ks = 0; ks < 2; ++ks) {
            const int koff = ks * 64 + lg * 16;
            const s16x8 ah = *(const s16x8*)(lds + AHI_OFF + abase + (koff ^ asw));
            const s16x8 al = *(const s16x8*)(lds + ALO_OFF + abase + (koff ^ asw));
            #pragma unroll
            for (int ct = 0; ct < 8; ++ct) {
                const int v    = (ct << 4) + lr;
                const int boff = koff ^ ((v & 7) << 4);
                const s16x8 bh = *(const s16x8*)(lds + BHI_OFF + v * 128 + boff);
                const s16x8 bl = *(const s16x8*)(lds + BLO_OFF + v * 128 + boff);
                acc[ct] = __builtin_amdgcn_mfma_f32_16x16x32_bf16(ah, bh, acc[ct], 0, 0, 0);
                acc[ct] = __builtin_amdgcn_mfma_f32_16x16x32_bf16(ah, bl, acc[ct], 0, 0, 0);
                acc[ct] = __builtin_amdgcn_mfma_f32_16x16x32_bf16(al, bh, acc[ct], 0, 0, 0);
            }
        }
        __syncthreads();                      // done reading tile t
        if (t + 1 < NT) { cvt_write(); __syncthreads(); }
    }

    // --- masked threshold count. C/D layout: col=lane&15, row=(lane>>4)*4+reg (m89) ---
    int am[4];
    #pragma unroll
    for (int r = 0; r < 4; ++r) am[r] = m1s[(w << 4) + lg * 4 + r];

    int lc = 0;
    #pragma unroll
    for (int ct = 0; ct < 8; ++ct) {
        const int bm = m2s[(ct << 4) + lr];
        #pragma unroll
        for (int r = 0; r < 4; ++r)
            lc += ((acc[ct][r] >= thr) & (am[r] != 0) & (bm != 0)) ? 1 : 0;
    }
    #pragma unroll
    for (int o = 32; o > 0; o >>= 1) lc += __shfl_down(lc, o);
    if ((tid & 63) == 0 && lc) atomicAdd(&sh_cnt, lc);
    __syncthreads();

    if (tid == 0) {
        const int nA = sh_nA;
        const float divisor = (nA == 0) ? 1e-7f : (float)nA;
        norm_out[bs] = (float)sh_cnt / divisor;
    }
}

// Tiny MLP head: h = tanh(norm @ Wh), out = sigmoid(h @ Ws)
__global__ __launch_bounds__(256) void head_kernel(
    const float* __restrict__ norm,
    const float* __restrict__ Wh,   // (S, HID) row-major
    const float* __restrict__ Ws,   // (HID, 1)
    float* __restrict__ out)
{
    int b = blockIdx.x * blockDim.x + threadIdx.x;
    if (b >= B_) return;
    fx4 n = *reinterpret_cast<const fx4*>(norm + b * 4);
    float score = 0.f;
    #pragma unroll
    for (int j = 0; j < HID_; ++j) {
        float h = n[0] * Wh[0 * HID_ + j] + n[1] * Wh[1 * HID_ + j]
                + n[2] * Wh[2 * HID_ + j] + n[3] * Wh[3 * HID_ + j];
        h = tanhf(h);
        score += h * Ws[j];
    }
    out[b] = 1.f / (1.f + expf(-score));
}

extern "C" void kernel_launch(void* const* d_in, const int* in_sizes, int n_in,
                              void* d_out, int out_size, void* d_ws, size_t ws_size,
                              hipStream_t stream)
{
    const float* t1  = (const float*)d_in[0];
    const float* t2  = (const float*)d_in[1];
    const int*   m1  = (const int*)d_in[2];
    const int*   m2  = (const int*)d_in[3];
    const float* thr = (const float*)d_in[4];
    const float* Wh  = (const float*)d_in[5];
    const float* Ws  = (const float*)d_in[6];
    float* out  = (float*)d_out;
    float* norm = (float*)d_ws;   // 1024 floats

    sim_count_mfma<<<B_ * S_, 256, 0, stream>>>(t1, t2, m1, m2, thr, norm);
    head_kernel<<<1, 256, 0, stream>>>(norm, Wh, Ws, out);
}